// Round 3
// baseline (644.286 us; speedup 1.0000x reference)
//
#include <hip/hip_runtime.h>

#define IN_DIM 4096
#define OUT_DIM 4096
#define RANK 16
#define MDIM 8192   // BATCH*SEQ = 4*2048

typedef unsigned short ushort_t;
typedef __attribute__((ext_vector_type(8))) short short8;   // 8 bf16 = 4 VGPRs (MFMA A/B frag)
typedef __attribute__((ext_vector_type(4))) float floatx4;  // MFMA C/D frag
typedef __attribute__((ext_vector_type(4))) ushort_t ushort4_t;
typedef __attribute__((ext_vector_type(2))) ushort_t ushort2_t;

__device__ __forceinline__ ushort_t f2b(float f) {
    union { float f; unsigned int i; } v; v.f = f;
    unsigned int u = v.i;
    u += 0x7FFFu + ((u >> 16) & 1u);   // round-to-nearest-even
    return (ushort_t)(u >> 16);
}

// async global->LDS, 16B per lane. LDS dest is wave-uniform base + lane*16.
#define GLOAD_LDS16(gp, lp)                                                    \
    __builtin_amdgcn_global_load_lds(                                          \
        (__attribute__((address_space(1))) void*)(gp),                         \
        (__attribute__((address_space(3))) void*)(lp), 16, 0, 0)

// ---------------------------------------------------------------------------
// Kernel 0: X fp32 -> bf16. Memory-bound (134 MB read, 67 MB write).
// ---------------------------------------------------------------------------
__global__ __launch_bounds__(256) void convx_kernel(
    const float4* __restrict__ x, ushort4_t* __restrict__ xb, int n4)
{
    int i = blockIdx.x * blockDim.x + threadIdx.x;
    int stride = gridDim.x * blockDim.x;
    for (; i < n4; i += stride) {
        float4 v = x[i];
        ushort4_t o;
        o.x = f2b(v.x); o.y = f2b(v.y); o.z = f2b(v.z); o.w = f2b(v.w);
        xb[i] = o;
    }
}

// ---------------------------------------------------------------------------
// Kernel 1: W_eff[o,i] = org[o,i] + (w1a@w1b)[o,i]*(w2a@w2b)[o,i]*scalar.
// B-columns in registers (2 i-cols/thread), A-rows via uniform ds_read_b128.
// ---------------------------------------------------------------------------
__global__ __launch_bounds__(256) void weff_kernel(
    const float* __restrict__ orgw,
    const float* __restrict__ w1a, const float* __restrict__ w1b,
    const float* __restrict__ w2a, const float* __restrict__ w2b,
    const float* __restrict__ scalar,
    ushort_t* __restrict__ weff)
{
    __shared__ float s1a[64 * RANK];   // 4 KB
    __shared__ float s2a[64 * RANK];   // 4 KB

    const int t  = threadIdx.x;
    const int i0 = blockIdx.x * 512 + t * 2;
    const int o0 = blockIdx.y * 64;

    for (int e = t; e < 64 * RANK; e += 256) {
        s1a[e] = w1a[o0 * RANK + e];
        s2a[e] = w2a[o0 * RANK + e];
    }

    float b1[RANK][2], b2[RANK][2];
    #pragma unroll
    for (int r = 0; r < RANK; ++r) {
        const float2 v1 = *(const float2*)&w1b[r * IN_DIM + i0];
        const float2 v2 = *(const float2*)&w2b[r * IN_DIM + i0];
        b1[r][0] = v1.x; b1[r][1] = v1.y;
        b2[r][0] = v2.x; b2[r][1] = v2.y;
    }
    __syncthreads();

    const float sc = scalar[0];
    for (int o = 0; o < 64; ++o) {
        float4 a1v[4], a2v[4];
        #pragma unroll
        for (int j = 0; j < 4; ++j) {
            a1v[j] = *(const float4*)&s1a[o * RANK + j * 4];
            a2v[j] = *(const float4*)&s2a[o * RANK + j * 4];
        }
        float p1_0 = 0.f, p1_1 = 0.f, p2_0 = 0.f, p2_1 = 0.f;
        #pragma unroll
        for (int j = 0; j < 4; ++j) {
            #pragma unroll
            for (int k = 0; k < 4; ++k) {
                const int r = j * 4 + k;
                const float a1 = (k == 0) ? a1v[j].x : (k == 1) ? a1v[j].y
                               : (k == 2) ? a1v[j].z : a1v[j].w;
                const float a2 = (k == 0) ? a2v[j].x : (k == 1) ? a2v[j].y
                               : (k == 2) ? a2v[j].z : a2v[j].w;
                p1_0 += a1 * b1[r][0]; p1_1 += a1 * b1[r][1];
                p2_0 += a2 * b2[r][0]; p2_1 += a2 * b2[r][1];
            }
        }
        const size_t idx = (size_t)(o0 + o) * IN_DIM + i0;
        const float2 ov = *(const float2*)&orgw[idx];
        ushort2_t st;
        st.x = f2b(ov.x + p1_0 * p2_0 * sc);
        st.y = f2b(ov.y + p1_1 * p2_1 * sc);
        *(ushort2_t*)&weff[idx] = st;
    }
}

// ---------------------------------------------------------------------------
// Kernel 2: out[m,o] = sum_k Xb[m,k]*W[o,k] + bias[o]  (bf16 in, fp32 out)
// 256x256 tile, BK=64, 8 waves (2Mx4N), 4-phase/K-tile pipelined schedule.
//
// R3: ONE-PHASE-LOOKAHEAD ds_reads. R2 showed reads<->MFMA fully serialized
// (phase 1529 cyc = 515 matrix + ~770 LDS-port + barriers). Fix: each read
// group is waited one full MFMA cluster after issue, so the LDS port drains
// UNDER the matrix pipe. Quadrant order LL->LH->HL->HH; P4 prefetches the
// NEXT K-tile's a_lo/b_lo (their old values die in P2/P3 -> no reg growth).
//
// Per K-tile T (consume buf_c = buf[T&1], buf_n = other):
//  P1: issue b_hi(4)+a_hi.lo(4) | stage A(T+1)h0->buf_n | BAR | lgkm(8)
//      [G1 done] | MFMA lo.lo | BAR
//  P2: issue a_hi.hi(4)         | stage A(T+1)h1->buf_n | BAR | lgkm(8)
//      [b_hi done] | MFMA lo.hi | BAR
//  P3: stage B(T+2)h0->buf_c | BAR | lgkm(0) [a_hi done] | MFMA hi.lo |
//      vmcnt(2) | BAR   <- publishes buf_n (A(T+1) by S1,S2; B(T+1) by
//                          prev S3,S4 all drained)
//  P4: issue G1'=a_lo,b_lo(12) from buf_n | stage B(T+2)h1->buf_c | BAR |
//      MFMA hi.hi (no wait) | BAR
//
// Hazard audit: stages into buf_c are B-region only; its readers (b_lo@P1
// wait, b_hi@P2 wait) provably complete before P2-close < S3 issue. buf_c
// A-region never written during consumption. G1' gated by P3's vmcnt+BAR.
// Next-half's B(T+3)->buf_n (S3') issues in P3' body, after P1'-close where
// lgkm(8) proved G1' complete. vmcnt: enter 4, +6, drain@P3 to 2, +2 = 4.
// DS waits valid (DS in-order per wave; no SMEM in loop).
// ---------------------------------------------------------------------------
#define BM 256
#define BN 256
#define BK 64

#define STAGE_A(buf, half, kcol)                                               \
    do {                                                                       \
        GLOAD_LDS16(gX0 + (size_t)(half) * (128 * IN_DIM) + (kcol),            \
                    (short*)&lA[buf][half][0][0] + w * 512);                   \
        GLOAD_LDS16(gX1 + (size_t)(half) * (128 * IN_DIM) + (kcol),            \
                    (short*)&lA[buf][half][0][0] + 4096 + w * 512);            \
    } while (0)

#define STAGE_B(buf, half, kcol)                                               \
    do {                                                                       \
        GLOAD_LDS16(gW0 + (size_t)(half) * (128 * IN_DIM) + (kcol),            \
                    (short*)&lB[buf][half][0][0] + w * 512);                   \
        GLOAD_LDS16(gW1 + (size_t)(half) * (128 * IN_DIM) + (kcol),            \
                    (short*)&lB[buf][half][0][0] + 4096 + w * 512);            \
    } while (0)

#define MFMA_(d, a, b) (d) = __builtin_amdgcn_mfma_f32_16x16x32_bf16((a), (b), (d), 0, 0, 0)

// 12 reads: next K-tile's a_lo (8) + b_lo (4)
#define READ_G1(aB, bB)                                                        \
    do {                                                                       \
        _Pragma("unroll")                                                      \
        for (int mi = 0; mi < 4; ++mi) {                                       \
            a_lo[mi][0] = *(const short8*)((aB) + mi * 1024 + ok0);            \
            a_lo[mi][1] = *(const short8*)((aB) + mi * 1024 + ok1);            \
        }                                                                      \
        _Pragma("unroll")                                                      \
        for (int ni = 0; ni < 2; ++ni) {                                       \
            b_lo[ni][0] = *(const short8*)((bB) + ni * 1024 + ok0);            \
            b_lo[ni][1] = *(const short8*)((bB) + ni * 1024 + ok1);            \
        }                                                                      \
    } while (0)

#define READ_G2(bB)                                                            \
    do {                                                                       \
        _Pragma("unroll")                                                      \
        for (int ni = 0; ni < 2; ++ni) {                                       \
            b_hi[ni][0] = *(const short8*)((bB) + 2048 + ni * 1024 + ok0);     \
            b_hi[ni][1] = *(const short8*)((bB) + 2048 + ni * 1024 + ok1);     \
        }                                                                      \
    } while (0)

#define READ_G3A(aB)                                                           \
    do {                                                                       \
        _Pragma("unroll")                                                      \
        for (int mi = 0; mi < 2; ++mi) {                                       \
            a_hi[mi][0] = *(const short8*)((aB) + 4096 + mi * 1024 + ok0);     \
            a_hi[mi][1] = *(const short8*)((aB) + 4096 + mi * 1024 + ok1);     \
        }                                                                      \
    } while (0)

#define READ_G3B(aB)                                                           \
    do {                                                                       \
        _Pragma("unroll")                                                      \
        for (int mi = 2; mi < 4; ++mi) {                                       \
            a_hi[mi][0] = *(const short8*)((aB) + 4096 + mi * 1024 + ok0);     \
            a_hi[mi][1] = *(const short8*)((aB) + 4096 + mi * 1024 + ok1);     \
        }                                                                      \
    } while (0)

#define Q_MFMA(mb, nb, afr, bfr)                                               \
    do {                                                                       \
        _Pragma("unroll")                                                      \
        for (int mi = 0; mi < 4; ++mi)                                         \
            _Pragma("unroll")                                                  \
            for (int ni = 0; ni < 2; ++ni) {                                   \
                MFMA_(acc[(mb) + mi][(nb) + ni], afr[mi][0], bfr[ni][0]);      \
                MFMA_(acc[(mb) + mi][(nb) + ni], afr[mi][1], bfr[ni][1]);      \
            }                                                                  \
    } while (0)

#define HALF_ITER(aBc, bBc, aBn, bBn, SS1, SS2, SS3, SS4)                      \
    do {                                                                       \
        /* P1 */                                                               \
        READ_G2(bBc);                                                          \
        READ_G3A(aBc);                                                         \
        __builtin_amdgcn_sched_barrier(0);                                     \
        SS1;                                                                   \
        __builtin_amdgcn_s_barrier();                                          \
        asm volatile("s_waitcnt lgkmcnt(8)" ::: "memory");                     \
        __builtin_amdgcn_sched_barrier(0);                                     \
        __builtin_amdgcn_s_setprio(1);                                         \
        Q_MFMA(0, 0, a_lo, b_lo);                                              \
        __builtin_amdgcn_s_setprio(0);                                         \
        __builtin_amdgcn_s_barrier();                                          \
        /* P2 */                                                               \
        READ_G3B(aBc);                                                         \
        __builtin_amdgcn_sched_barrier(0);                                     \
        SS2;                                                                   \
        __builtin_amdgcn_s_barrier();                                          \
        asm volatile("s_waitcnt lgkmcnt(8)" ::: "memory");                     \
        __builtin_amdgcn_sched_barrier(0);                                     \
        __builtin_amdgcn_s_setprio(1);                                         \
        Q_MFMA(0, 2, a_lo, b_hi);                                              \
        __builtin_amdgcn_s_setprio(0);                                         \
        __builtin_amdgcn_s_barrier();                                          \
        /* P3 */                                                               \
        SS3;                                                                   \
        __builtin_amdgcn_s_barrier();                                          \
        asm volatile("s_waitcnt lgkmcnt(0)" ::: "memory");                     \
        __builtin_amdgcn_sched_barrier(0);                                     \
        __builtin_amdgcn_s_setprio(1);                                         \
        Q_MFMA(4, 0, a_hi, b_lo);                                              \
        __builtin_amdgcn_s_setprio(0);                                         \
        asm volatile("s_waitcnt vmcnt(2)" ::: "memory");                       \
        __builtin_amdgcn_s_barrier();                                          \
        /* P4: prefetch next K-tile's G1 from just-published buf_n */          \
        READ_G1(aBn, bBn);                                                     \
        __builtin_amdgcn_sched_barrier(0);                                     \
        SS4;                                                                   \
        __builtin_amdgcn_s_barrier();                                          \
        __builtin_amdgcn_sched_barrier(0);                                     \
        __builtin_amdgcn_s_setprio(1);                                         \
        Q_MFMA(4, 2, a_hi, b_hi);                                              \
        __builtin_amdgcn_s_setprio(0);                                         \
        __builtin_amdgcn_s_barrier();                                          \
    } while (0)

__global__ __launch_bounds__(512, 2) void gemm_kernel(
    const ushort_t* __restrict__ X,     // [MDIM, IN_DIM] bf16
    const ushort_t* __restrict__ W,     // [OUT_DIM, IN_DIM] bf16 (= W_eff)
    const float* __restrict__ bias,     // [OUT_DIM] fp32
    float* __restrict__ out)            // [MDIM, OUT_DIM] fp32
{
    __shared__ __align__(16) short lA[2][2][128][64];   // 64 KiB
    __shared__ __align__(16) short lB[2][2][128][64];   // 64 KiB

    const int t    = threadIdx.x;
    const int w    = t >> 6;        // wave 0..7
    const int lane = t & 63;
    const int quad = lane >> 4;     // 0..3
    const int r16  = lane & 15;
    const int wm   = w >> 2;        // 0..1 -> 128 m-rows
    const int wn   = w & 3;         // 0..3 -> 64 n-cols

    // T1: bijective XCD swizzle (512 wgs, 512 % 8 == 0 -> simple form valid)
    const int bid = blockIdx.y * gridDim.x + blockIdx.x;   // 0..511
    const int swz = (bid & 7) * 64 + (bid >> 3);
    const int m0  = (swz >> 4) * BM;
    const int n0  = (swz & 15) * BN;

    // Staging: thread covers 16B-slots s0 (j=0) and s1 (j=1) of each half.
    // Slot s holds chunk (row=s>>3, k8=(s&7)^(row&7)) -> XOR folded into the
    // per-lane global source address; LDS dest stays linear.
    const int s0  = w * 64 + lane;
    const int s1  = 512 + s0;
    const int r0  = s0 >> 3, r1 = s1 >> 3;
    const int k80 = (s0 & 7) ^ (r0 & 7);
    const int k81 = (s1 & 7) ^ (r1 & 7);
    const ushort_t* gX0 = X + (size_t)(m0 + r0) * IN_DIM + k80 * 8;
    const ushort_t* gX1 = X + (size_t)(m0 + r1) * IN_DIM + k81 * 8;
    const ushort_t* gW0 = W + (size_t)(n0 + r0) * IN_DIM + k80 * 8;
    const ushort_t* gW1 = W + (size_t)(n0 + r1) * IN_DIM + k81 * 8;

    // Fragment read bases (swizzled k-offsets; 2-way bank aliasing = free)
    const short* aB0 = &lA[0][wm][r16][0];
    const short* aB1 = &lA[1][wm][r16][0];
    const short* bB0 = &lB[0][wn >> 1][(wn & 1) * 64 + r16][0];
    const short* bB1 = &lB[1][wn >> 1][(wn & 1) * 64 + r16][0];
    const int ok0 = ((0 + quad) ^ (r16 & 7)) << 3;   // kk=0
    const int ok1 = ((4 + quad) ^ (r16 & 7)) << 3;   // kk=1

    floatx4 acc[8][4];
    #pragma unroll
    for (int i = 0; i < 8; ++i)
        #pragma unroll
        for (int j = 0; j < 4; ++j)
            acc[i][j] = (floatx4){0.f, 0.f, 0.f, 0.f};

    // Loop-carried fragment registers (G1 written in P4, consumed next P1).
    short8 a_lo[4][2], a_hi[4][2], b_lo[2][2], b_hi[2][2];

    // Prologue: K-tile 0 fully -> buf0 (8 loads); B(1) -> buf1 (4 loads,
    // playing the role of steady-state S3/S4 of "H-1").
    STAGE_A(0, 0, 0);
    STAGE_A(0, 1, 0);
    STAGE_B(0, 0, 0);
    STAGE_B(0, 1, 0);
    STAGE_B(1, 0, 64);
    STAGE_B(1, 1, 64);
    asm volatile("s_waitcnt vmcnt(4)" ::: "memory");   // buf0 landed; B(1) in flight
    __builtin_amdgcn_s_barrier();                      // publish buf0
    READ_G1(aB0, bB0);                                 // G1 for K-tile 0
    __builtin_amdgcn_sched_barrier(0);

    for (int it = 0; it < IN_DIM / 128; ++it) {
        const int kmax = IN_DIM - 64;
        int kA1 = it * 128 + 64;  if (kA1 > kmax) kA1 = kmax;   // A of K-tile T+1 (even T)
        int kB2 = it * 128 + 128; if (kB2 > kmax) kB2 = kmax;   // B of T+2 / A of T+2
        int kB3 = it * 128 + 192; if (kB3 > kmax) kB3 = kmax;   // B of K-tile T+3

        // even K-tile T=2it: buf_c = buf0, buf_n = buf1
        HALF_ITER(aB0, bB0, aB1, bB1,
                  STAGE_A(1, 0, kA1), STAGE_A(1, 1, kA1),
                  STAGE_B(0, 0, kB2), STAGE_B(0, 1, kB2));
        // odd K-tile T=2it+1: buf_c = buf1, buf_n = buf0
        HALF_ITER(aB1, bB1, aB0, bB0,
                  STAGE_A(0, 0, kB2), STAGE_A(0, 1, kB2),
                  STAGE_B(1, 0, kB3), STAGE_B(1, 1, kB3));
    }

    // Epilogue. C/D layout: col = lane&15 (n), row = quad*4 + reg (m).
    #pragma unroll
    for (int ni = 0; ni < 4; ++ni) {
        const int gn = n0 + wn * 64 + ni * 16 + r16;
        const float bv = bias[gn];
        #pragma unroll
        for (int mi = 0; mi < 8; ++mi) {
            const int gm = m0 + wm * 128 + mi * 16 + quad * 4;
            #pragma unroll
            for (int rr = 0; rr < 4; ++rr)
                out[(size_t)(gm + rr) * OUT_DIM + gn] = acc[mi][ni][rr] + bv;
        }
    }
}

extern "C" void kernel_launch(void* const* d_in, const int* in_sizes, int n_in,
                              void* d_out, int out_size, void* d_ws, size_t ws_size,
                              hipStream_t stream) {
    const float* x      = (const float*)d_in[0];  // [4,2048,4096] fp32
    const float* orgw   = (const float*)d_in[1];  // [4096,4096] fp32
    const float* bias   = (const float*)d_in[2];  // [4096] fp32
    const float* w1a    = (const float*)d_in[3];  // [4096,16] fp32
    const float* w1b    = (const float*)d_in[4];  // [16,4096] fp32
    const float* w2a    = (const float*)d_in[5];  // [4096,16] fp32
    const float* w2b    = (const float*)d_in[6];  // [16,4096] fp32
    const float* scalar = (const float*)d_in[7];  // [1] fp32

    // workspace layout: [0, 64MB) X bf16; [64MB, 96MB) W_eff bf16
    ushort_t* xb   = (ushort_t*)d_ws;
    ushort_t* weff = (ushort_t*)d_ws + (size_t)MDIM * IN_DIM;
    float* out = (float*)d_out;

    const int n4 = MDIM * IN_DIM / 4;
    convx_kernel<<<2048, 256, 0, stream>>>((const float4*)x, (ushort4_t*)xb, n4);
    weff_kernel<<<dim3(IN_DIM / 512, OUT_DIM / 64), 256, 0, stream>>>(
        orgw, w1a, w1b, w2a, w2b, scalar, weff);
    gemm_kernel<<<dim3(OUT_DIM / BN, MDIM / BM), 512, 0, stream>>>(
        xb, weff, bias, out);
}

// Round 4
// 556.713 us; speedup vs baseline: 1.1573x; 1.1573x over previous
//
#include <hip/hip_runtime.h>

#define IN_DIM 4096
#define OUT_DIM 4096
#define RANK 16
#define MDIM 8192   // BATCH*SEQ = 4*2048

typedef unsigned short ushort_t;
typedef __attribute__((ext_vector_type(8))) short short8;   // 8 bf16 = 4 VGPRs (MFMA A/B frag)
typedef __attribute__((ext_vector_type(4))) float floatx4;  // MFMA C/D frag
typedef __attribute__((ext_vector_type(4))) ushort_t ushort4_t;
typedef __attribute__((ext_vector_type(2))) ushort_t ushort2_t;

__device__ __forceinline__ ushort_t f2b(float f) {
    union { float f; unsigned int i; } v; v.f = f;
    unsigned int u = v.i;
    u += 0x7FFFu + ((u >> 16) & 1u);   // round-to-nearest-even
    return (ushort_t)(u >> 16);
}

// async global->LDS, 16B per lane. LDS dest is wave-uniform base + lane*16.
#define GLOAD_LDS16(gp, lp)                                                    \
    __builtin_amdgcn_global_load_lds(                                          \
        (__attribute__((address_space(1))) void*)(gp),                         \
        (__attribute__((address_space(3))) void*)(lp), 16, 0, 0)

// ---------------------------------------------------------------------------
// Fused prep kernel. Two independent memory-bound jobs run concurrently:
//   blocks [0, 512):    weff  — W_eff[o,i] = org + (w1a@w1b)*(w2a@w2b)*scalar
//                       (B-cols in regs, A-rows via uniform ds_read_b128)
//   blocks [512, 2560): convx — X fp32 -> bf16 streaming convert
// Fusing removes one launch and overlaps the two HBM streams (297 MB total).
// ---------------------------------------------------------------------------
__global__ __launch_bounds__(256) void prep_kernel(
    const float4* __restrict__ x, ushort4_t* __restrict__ xb, int n4,
    const float* __restrict__ orgw,
    const float* __restrict__ w1a, const float* __restrict__ w1b,
    const float* __restrict__ w2a, const float* __restrict__ w2b,
    const float* __restrict__ scalar,
    ushort_t* __restrict__ weff)
{
    __shared__ float s1a[64 * RANK];   // 4 KB
    __shared__ float s2a[64 * RANK];   // 4 KB

    const int bid = blockIdx.x;
    const int t   = threadIdx.x;

    if (bid < 512) {
        // ---- weff role: 64 o-rows x 512 i-cols per block ----
        const int i0 = (bid & 7) * 512 + t * 2;
        const int o0 = (bid >> 3) * 64;

        for (int e = t; e < 64 * RANK; e += 256) {
            s1a[e] = w1a[o0 * RANK + e];
            s2a[e] = w2a[o0 * RANK + e];
        }

        float b1[RANK][2], b2[RANK][2];
        #pragma unroll
        for (int r = 0; r < RANK; ++r) {
            const float2 v1 = *(const float2*)&w1b[r * IN_DIM + i0];
            const float2 v2 = *(const float2*)&w2b[r * IN_DIM + i0];
            b1[r][0] = v1.x; b1[r][1] = v1.y;
            b2[r][0] = v2.x; b2[r][1] = v2.y;
        }
        __syncthreads();

        const float sc = scalar[0];
        #pragma unroll 2
        for (int o = 0; o < 64; ++o) {
            const size_t idx = (size_t)(o0 + o) * IN_DIM + i0;
            const float2 ov = *(const float2*)&orgw[idx];   // issue early
            float4 a1v[4], a2v[4];
            #pragma unroll
            for (int j = 0; j < 4; ++j) {
                a1v[j] = *(const float4*)&s1a[o * RANK + j * 4];
                a2v[j] = *(const float4*)&s2a[o * RANK + j * 4];
            }
            float p1_0 = 0.f, p1_1 = 0.f, p2_0 = 0.f, p2_1 = 0.f;
            #pragma unroll
            for (int j = 0; j < 4; ++j) {
                #pragma unroll
                for (int k = 0; k < 4; ++k) {
                    const int r = j * 4 + k;
                    const float a1 = (k == 0) ? a1v[j].x : (k == 1) ? a1v[j].y
                                   : (k == 2) ? a1v[j].z : a1v[j].w;
                    const float a2 = (k == 0) ? a2v[j].x : (k == 1) ? a2v[j].y
                                   : (k == 2) ? a2v[j].z : a2v[j].w;
                    p1_0 += a1 * b1[r][0]; p1_1 += a1 * b1[r][1];
                    p2_0 += a2 * b2[r][0]; p2_1 += a2 * b2[r][1];
                }
            }
            ushort2_t st;
            st.x = f2b(ov.x + p1_0 * p2_0 * sc);
            st.y = f2b(ov.y + p1_1 * p2_1 * sc);
            *(ushort2_t*)&weff[idx] = st;
        }
    } else {
        // ---- convx role: grid-stride fp32 -> bf16 ----
        const int nblk = 2048;
        int i = (bid - 512) * 256 + t;
        const int stride = nblk * 256;
        for (; i < n4; i += stride) {
            float4 v = x[i];
            ushort4_t o;
            o.x = f2b(v.x); o.y = f2b(v.y); o.z = f2b(v.z); o.w = f2b(v.w);
            xb[i] = o;
        }
    }
}

// ---------------------------------------------------------------------------
// Kernel 2: out[m,o] = sum_k Xb[m,k]*W[o,k] + bias[o]  (bf16 in, fp32 out)
// 256x256 tile, BK=64, 8 waves (2Mx4N), 8-phase pipelined schedule
// (T1 XCD swizzle + T2 XOR-swizzled LDS + T3/T4 counted vmcnt + T5 setprio).
// EXACT R1 version (best measured: 311 us). R2/R3 scheduling experiments
// regressed; per-phase accounting shows port<->MFMA serialization is
// structural to the 1-block lockstep-barrier skeleton.
// ---------------------------------------------------------------------------
#define BM 256
#define BN 256
#define BK 64

#define STAGE_A(buf, half, kcol)                                               \
    do {                                                                       \
        GLOAD_LDS16(gX0 + (size_t)(half) * (128 * IN_DIM) + (kcol),            \
                    (short*)&lA[buf][half][0][0] + w * 512);                   \
        GLOAD_LDS16(gX1 + (size_t)(half) * (128 * IN_DIM) + (kcol),            \
                    (short*)&lA[buf][half][0][0] + 4096 + w * 512);            \
    } while (0)

#define STAGE_B(buf, half, kcol)                                               \
    do {                                                                       \
        GLOAD_LDS16(gW0 + (size_t)(half) * (128 * IN_DIM) + (kcol),            \
                    (short*)&lB[buf][half][0][0] + w * 512);                   \
        GLOAD_LDS16(gW1 + (size_t)(half) * (128 * IN_DIM) + (kcol),            \
                    (short*)&lB[buf][half][0][0] + 4096 + w * 512);            \
    } while (0)

#define MFMA_(d, a, b) (d) = __builtin_amdgcn_mfma_f32_16x16x32_bf16((a), (b), (d), 0, 0, 0)

#define HALF_ITER(aB, bB, S1, S2, S3, S4)                                      \
    do {                                                                       \
        short8 a_lo[4][2], a_hi[4][2], b_lo[2][2], b_hi[2][2];                 \
        /* P1: read A-mlo + B-nlo, stage S1, mfma mlo x nlo */                 \
        _Pragma("unroll")                                                      \
        for (int mi = 0; mi < 4; ++mi) {                                       \
            a_lo[mi][0] = *(const short8*)((aB) + mi * 1024 + ok0);            \
            a_lo[mi][1] = *(const short8*)((aB) + mi * 1024 + ok1);            \
        }                                                                      \
        _Pragma("unroll")                                                      \
        for (int ni = 0; ni < 2; ++ni) {                                       \
            b_lo[ni][0] = *(const short8*)((bB) + ni * 1024 + ok0);            \
            b_lo[ni][1] = *(const short8*)((bB) + ni * 1024 + ok1);            \
        }                                                                      \
        S1;                                                                    \
        __builtin_amdgcn_s_barrier();                                          \
        asm volatile("s_waitcnt lgkmcnt(0)" ::: "memory");                     \
        __builtin_amdgcn_s_setprio(1);                                         \
        _Pragma("unroll")                                                      \
        for (int mi = 0; mi < 4; ++mi)                                         \
            _Pragma("unroll")                                                  \
            for (int ni = 0; ni < 2; ++ni) {                                   \
                MFMA_(acc[mi][ni], a_lo[mi][0], b_lo[ni][0]);                  \
                MFMA_(acc[mi][ni], a_lo[mi][1], b_lo[ni][1]);                  \
            }                                                                  \
        __builtin_amdgcn_s_setprio(0);                                         \
        __builtin_amdgcn_s_barrier();                                          \
        /* P2: read A-mhi, stage S2, mfma mhi x nlo */                         \
        _Pragma("unroll")                                                      \
        for (int mi = 0; mi < 4; ++mi) {                                       \
            a_hi[mi][0] = *(const short8*)((aB) + 4096 + mi * 1024 + ok0);     \
            a_hi[mi][1] = *(const short8*)((aB) + 4096 + mi * 1024 + ok1);     \
        }                                                                      \
        S2;                                                                    \
        __builtin_amdgcn_s_barrier();                                          \
        asm volatile("s_waitcnt lgkmcnt(0)" ::: "memory");                     \
        __builtin_amdgcn_s_setprio(1);                                         \
        _Pragma("unroll")                                                      \
        for (int mi = 0; mi < 4; ++mi)                                         \
            _Pragma("unroll")                                                  \
            for (int ni = 0; ni < 2; ++ni) {                                   \
                MFMA_(acc[4 + mi][ni], a_hi[mi][0], b_lo[ni][0]);              \
                MFMA_(acc[4 + mi][ni], a_hi[mi][1], b_lo[ni][1]);              \
            }                                                                  \
        __builtin_amdgcn_s_setprio(0);                                         \
        __builtin_amdgcn_s_barrier();                                          \
        /* P3: read B-nhi, stage S3, mfma mhi x nhi */                         \
        _Pragma("unroll")                                                      \
        for (int ni = 0; ni < 2; ++ni) {                                       \
            b_hi[ni][0] = *(const short8*)((bB) + 2048 + ni * 1024 + ok0);     \
            b_hi[ni][1] = *(const short8*)((bB) + 2048 + ni * 1024 + ok1);     \
        }                                                                      \
        S3;                                                                    \
        __builtin_amdgcn_s_barrier();                                          \
        asm volatile("s_waitcnt lgkmcnt(0)" ::: "memory");                     \
        __builtin_amdgcn_s_setprio(1);                                         \
        _Pragma("unroll")                                                      \
        for (int mi = 0; mi < 4; ++mi)                                         \
            _Pragma("unroll")                                                  \
            for (int ni = 0; ni < 2; ++ni) {                                   \
                MFMA_(acc[4 + mi][2 + ni], a_hi[mi][0], b_hi[ni][0]);          \
                MFMA_(acc[4 + mi][2 + ni], a_hi[mi][1], b_hi[ni][1]);          \
            }                                                                  \
        __builtin_amdgcn_s_setprio(0);                                         \
        __builtin_amdgcn_s_barrier();                                          \
        /* P4: stage S4, mfma mlo x nhi, counted vmcnt before closing bar */   \
        S4;                                                                    \
        __builtin_amdgcn_s_barrier();                                          \
        __builtin_amdgcn_s_setprio(1);                                         \
        _Pragma("unroll")                                                      \
        for (int mi = 0; mi < 4; ++mi)                                         \
            _Pragma("unroll")                                                  \
            for (int ni = 0; ni < 2; ++ni) {                                   \
                MFMA_(acc[mi][2 + ni], a_lo[mi][0], b_hi[ni][0]);              \
                MFMA_(acc[mi][2 + ni], a_lo[mi][1], b_hi[ni][1]);              \
            }                                                                  \
        __builtin_amdgcn_s_setprio(0);                                         \
        asm volatile("s_waitcnt vmcnt(4)" ::: "memory");                       \
        __builtin_amdgcn_s_barrier();                                          \
    } while (0)

__global__ __launch_bounds__(512, 2) void gemm_kernel(
    const ushort_t* __restrict__ X,     // [MDIM, IN_DIM] bf16
    const ushort_t* __restrict__ W,     // [OUT_DIM, IN_DIM] bf16 (= W_eff)
    const float* __restrict__ bias,     // [OUT_DIM] fp32
    float* __restrict__ out)            // [MDIM, OUT_DIM] fp32
{
    __shared__ __align__(16) short lA[2][2][128][64];   // 64 KiB
    __shared__ __align__(16) short lB[2][2][128][64];   // 64 KiB

    const int t    = threadIdx.x;
    const int w    = t >> 6;        // wave 0..7
    const int lane = t & 63;
    const int quad = lane >> 4;     // 0..3
    const int r16  = lane & 15;
    const int wm   = w >> 2;        // 0..1 -> 128 m-rows
    const int wn   = w & 3;         // 0..3 -> 64 n-cols

    // T1: bijective XCD swizzle (512 wgs, 512 % 8 == 0 -> simple form valid)
    const int bid = blockIdx.y * gridDim.x + blockIdx.x;   // 0..511
    const int swz = (bid & 7) * 64 + (bid >> 3);
    const int m0  = (swz >> 4) * BM;
    const int n0  = (swz & 15) * BN;

    // Staging: thread covers 16B-slots s0 (j=0) and s1 (j=1) of each half.
    // Slot s holds chunk (row=s>>3, k8=(s&7)^(row&7)) -> XOR folded into the
    // per-lane global source address; LDS dest stays linear.
    const int s0  = w * 64 + lane;
    const int s1  = 512 + s0;
    const int r0  = s0 >> 3, r1 = s1 >> 3;
    const int k80 = (s0 & 7) ^ (r0 & 7);
    const int k81 = (s1 & 7) ^ (r1 & 7);
    const ushort_t* gX0 = X + (size_t)(m0 + r0) * IN_DIM + k80 * 8;
    const ushort_t* gX1 = X + (size_t)(m0 + r1) * IN_DIM + k81 * 8;
    const ushort_t* gW0 = W + (size_t)(n0 + r0) * IN_DIM + k80 * 8;
    const ushort_t* gW1 = W + (size_t)(n0 + r1) * IN_DIM + k81 * 8;

    // Fragment read bases (swizzled k-offsets; 2-way bank aliasing = free)
    const short* aB0 = &lA[0][wm][r16][0];
    const short* aB1 = &lA[1][wm][r16][0];
    const short* bB0 = &lB[0][wn >> 1][(wn & 1) * 64 + r16][0];
    const short* bB1 = &lB[1][wn >> 1][(wn & 1) * 64 + r16][0];
    const int ok0 = ((0 + quad) ^ (r16 & 7)) << 3;   // kk=0
    const int ok1 = ((4 + quad) ^ (r16 & 7)) << 3;   // kk=1

    floatx4 acc[8][4];
    #pragma unroll
    for (int i = 0; i < 8; ++i)
        #pragma unroll
        for (int j = 0; j < 4; ++j)
            acc[i][j] = (floatx4){0.f, 0.f, 0.f, 0.f};

    // Prologue: buf0 fully (K-tile 0, 8 loads) + buf1 A halves (K-tile 1).
    // vmcnt(4) forces buf0 landed, leaves buf1-A in flight.
    STAGE_A(0, 0, 0);
    STAGE_A(0, 1, 0);
    STAGE_B(0, 0, 0);
    STAGE_B(0, 1, 0);
    STAGE_A(1, 0, 64);
    STAGE_A(1, 1, 64);
    asm volatile("s_waitcnt vmcnt(4)" ::: "memory");
    __builtin_amdgcn_s_barrier();

    for (int it = 0; it < IN_DIM / 128; ++it) {
        const int kmax = IN_DIM - 64;
        int kB1 = it * 128 + 64;  if (kB1 > kmax) kB1 = kmax;   // B of K-tile T+1
        int kA2 = it * 128 + 128; if (kA2 > kmax) kA2 = kmax;   // A,B of K-tile T+2
        int kA3 = it * 128 + 192; if (kA3 > kmax) kA3 = kmax;   // A of K-tile T+3

        HALF_ITER(aB0, bB0,
                  STAGE_B(1, 0, kB1), STAGE_B(1, 1, kB1),
                  STAGE_A(0, 0, kA2), STAGE_A(0, 1, kA2));
        HALF_ITER(aB1, bB1,
                  STAGE_B(0, 0, kA2), STAGE_B(0, 1, kA2),
                  STAGE_A(1, 0, kA3), STAGE_A(1, 1, kA3));
    }

    // Epilogue. C/D layout: col = lane&15 (n), row = quad*4 + reg (m).
    #pragma unroll
    for (int ni = 0; ni < 4; ++ni) {
        const int gn = n0 + wn * 64 + ni * 16 + r16;
        const float bv = bias[gn];
        #pragma unroll
        for (int mi = 0; mi < 8; ++mi) {
            const int gm = m0 + wm * 128 + mi * 16 + quad * 4;
            #pragma unroll
            for (int rr = 0; rr < 4; ++rr)
                out[(size_t)(gm + rr) * OUT_DIM + gn] = acc[mi][ni][rr] + bv;
        }
    }
}

extern "C" void kernel_launch(void* const* d_in, const int* in_sizes, int n_in,
                              void* d_out, int out_size, void* d_ws, size_t ws_size,
                              hipStream_t stream) {
    const float* x      = (const float*)d_in[0];  // [4,2048,4096] fp32
    const float* orgw   = (const float*)d_in[1];  // [4096,4096] fp32
    const float* bias   = (const float*)d_in[2];  // [4096] fp32
    const float* w1a    = (const float*)d_in[3];  // [4096,16] fp32
    const float* w1b    = (const float*)d_in[4];  // [16,4096] fp32
    const float* w2a    = (const float*)d_in[5];  // [4096,16] fp32
    const float* w2b    = (const float*)d_in[6];  // [16,4096] fp32
    const float* scalar = (const float*)d_in[7];  // [1] fp32

    // workspace layout: [0, 64MB) X bf16; [64MB, 96MB) W_eff bf16
    ushort_t* xb   = (ushort_t*)d_ws;
    ushort_t* weff = (ushort_t*)d_ws + (size_t)MDIM * IN_DIM;
    float* out = (float*)d_out;

    const int n4 = MDIM * IN_DIM / 4;
    prep_kernel<<<2560, 256, 0, stream>>>(
        (const float4*)x, (ushort4_t*)xb, n4,
        orgw, w1a, w1b, w2a, w2b, scalar, weff);
    gemm_kernel<<<dim3(OUT_DIM / BN, MDIM / BM), 512, 0, stream>>>(
        xb, weff, bias, out);
}